// Round 1
// baseline (91.162 us; speedup 1.0000x reference)
//
#include <hip/hip_runtime.h>
#include <hip/hip_bf16.h>

// Fused per-object-type output projection:
//   out[b, f, t] = mask(f < jc[e]*6) * ( sum_d X[t,b,d] * W[e,d,f] + bias[e,f] ),  e = object_types[b]
// One GEMM per sample: M=768 feats, N=196 frames (pad 208), K=1024, bf16 MFMA, f32 accum.

#define NFRAMES 196
#define TPAD    208
#define BSZ     128
#define DLAT    1024
#define FIN     768
#define BM      128
#define BK      32
#define KSTEPS  (DLAT / BK)   // 32
#define MTILES  (FIN / BM)    // 6
#define NFRAG   (TPAD / 16)   // 13
#define NTHREADS 256

typedef short bf16x8 __attribute__((ext_vector_type(8)));
typedef short s16x4  __attribute__((ext_vector_type(4)));
typedef float f32x4  __attribute__((ext_vector_type(4)));

// 16B-chunk XOR swizzle: read (16 consecutive rows, fixed chunk) -> 2-way (free);
// staged writes (4-row-strided threads, rotated rounds) -> 4-way.
__device__ __forceinline__ int swz(int r) { return ((r >> 2) & 3) ^ ((r >> 1) & 1); }

__device__ __forceinline__ short f2bf(float f) {
    __hip_bfloat16 h = __float2bfloat16(f);   // RNE
    return __builtin_bit_cast(short, h);
}

// barrier that does NOT drain vmcnt (keeps prefetch global loads in flight)
#define BAR() do { asm volatile("s_waitcnt lgkmcnt(0)" ::: "memory"); \
                   __builtin_amdgcn_s_barrier(); } while (0)

__global__ __launch_bounds__(NTHREADS, 2)
void fused_expert_gemm(const float* __restrict__ X,      // (196,128,1024)
                       const int*   __restrict__ otypes, // (128)
                       const float* __restrict__ W,      // (16,1024,768)
                       const float* __restrict__ Bias,   // (16,768)
                       const int*   __restrict__ jc,     // (16)
                       float*       __restrict__ out)    // (128,768,196)
{
    __shared__ short As[BM * BK];    // A = W^T tile: [m][k] swizzled, rows of 64B
    __shared__ short Bs[TPAD * BK];  // B = X tile:   [t][k] swizzled

    // XCD chunk swizzle: 768 blocks, 96 consecutive logical blocks per XCD so the
    // 6 M-tiles of one sample (same 800KB X slice) share one L2.
    const int hw      = blockIdx.x;
    const int logical = (hw & 7) * ((MTILES * BSZ) / 8) + (hw >> 3);
    const int b       = logical / MTILES;
    const int mt      = logical - b * MTILES;
    const int m0      = mt * BM;

    const int tid = threadIdx.x;
    const int e   = otypes[b];

    // A staging: thread owns a 4k x 4m micro-block (micro-transpose in regs)
    const int kb = tid >> 5;   // 0..7  -> k = 4*kb
    const int mb = tid & 31;   // 0..31 -> m = 4*mb
    // B staging: thread owns 4 consecutive k of one row, 32 rows/pass
    const int kq = tid & 7;    // 0..7  -> k = 4*kq
    const int rp = tid >> 3;   // 0..31 row-in-pass

    const f32x4* __restrict__ Xv = reinterpret_cast<const f32x4*>(X);
    const f32x4* __restrict__ Wv = reinterpret_cast<const f32x4*>(W);
    const f32x4 fzero = {0.f, 0.f, 0.f, 0.f};

    f32x4 wa[4];  // prefetched W rows (4 k, 4 m each)
    f32x4 xb[7];  // prefetched X (7 passes x 4 k)

    const int wave = tid >> 6;
    const int lane = tid & 63;
    const int lr   = lane & 15;
    const int g    = lane >> 4;

    f32x4 acc[2][NFRAG];
    #pragma unroll
    for (int i = 0; i < 2; ++i)
        #pragma unroll
        for (int j = 0; j < NFRAG; ++j) acc[i][j] = fzero;

    auto load_stage = [&](int k0) {
        #pragma unroll
        for (int i = 0; i < 4; ++i)
            wa[i] = Wv[(size_t)(e * DLAT + k0 + kb * 4 + i) * (FIN / 4) + (m0 >> 2) + mb];
        #pragma unroll
        for (int p = 0; p < 7; ++p) {
            const int n = p * 32 + rp;
            if (n < NFRAMES)
                xb[p] = Xv[((size_t)n * BSZ + b) * (DLAT / 4) + (k0 >> 2) + kq];
            else
                xb[p] = fzero;   // frame padding -> zeros
        }
    };

    auto write_stage = [&]() {
        // A: transpose 4x4, rotated row order so a wave's writes spread banks
        #pragma unroll
        for (int j = 0; j < 4; ++j) {
            const int mm = (mb + j) & 3;
            const int m  = mb * 4 + mm;
            s16x4 v;
            v[0] = f2bf(wa[0][mm]); v[1] = f2bf(wa[1][mm]);
            v[2] = f2bf(wa[2][mm]); v[3] = f2bf(wa[3][mm]);
            const int ea = m * 32 + (((kb >> 1) ^ swz(m)) << 3) + (kb & 1) * 4;
            *reinterpret_cast<s16x4*>(&As[ea]) = v;
        }
        // B: k already contiguous, straight 8B writes
        #pragma unroll
        for (int p = 0; p < 7; ++p) {
            const int n = p * 32 + rp;
            if (n < TPAD) {
                s16x4 v;
                v[0] = f2bf(xb[p][0]); v[1] = f2bf(xb[p][1]);
                v[2] = f2bf(xb[p][2]); v[3] = f2bf(xb[p][3]);
                const int ea = n * 32 + (((kq >> 1) ^ swz(n)) << 3) + (kq & 1) * 4;
                *reinterpret_cast<s16x4*>(&Bs[ea]) = v;
            }
        }
    };

    load_stage(0);

    #pragma unroll 1
    for (int ks = 0; ks < KSTEPS; ++ks) {
        BAR();                 // previous compute's LDS reads done
        write_stage();         // regs -> LDS (compiler inserts vmcnt waits on uses)
        if (ks + 1 < KSTEPS)
            load_stage((ks + 1) * BK);   // issue next tile's global loads early
        BAR();                 // LDS writes visible; vmcnt stays in flight

        const int ma0 = wave * 32 + lr;
        const int ma1 = ma0 + 16;
        bf16x8 a0 = *reinterpret_cast<const bf16x8*>(&As[ma0 * 32 + ((g ^ swz(ma0)) << 3)]);
        bf16x8 a1 = *reinterpret_cast<const bf16x8*>(&As[ma1 * 32 + ((g ^ swz(ma1)) << 3)]);
        #pragma unroll
        for (int nf = 0; nf < NFRAG; ++nf) {
            const int nr = nf * 16 + lr;
            bf16x8 bf = *reinterpret_cast<const bf16x8*>(&Bs[nr * 32 + ((g ^ swz(nr)) << 3)]);
            acc[0][nf] = __builtin_amdgcn_mfma_f32_16x16x32_bf16(a0, bf, acc[0][nf], 0, 0, 0);
            acc[1][nf] = __builtin_amdgcn_mfma_f32_16x16x32_bf16(a1, bf, acc[1][nf], 0, 0, 0);
        }
    }

    // Epilogue: bias + column mask, write everything (out buffer is poisoned)
    const int   fcb   = jc[e] * 6;
    const float* biasE = Bias + e * FIN;
    float*       outB  = out + (size_t)b * (FIN * NFRAMES);

    #pragma unroll
    for (int mf = 0; mf < 2; ++mf) {
        #pragma unroll
        for (int r = 0; r < 4; ++r) {
            const int fcol = m0 + wave * 32 + mf * 16 + g * 4 + r;  // C row = (lane>>4)*4 + reg
            const float bv = biasE[fcol];
            const bool valid = fcol < fcb;
            #pragma unroll
            for (int nf = 0; nf < NFRAG; ++nf) {
                const int t = nf * 16 + lr;                          // C col = lane&15
                if (t < NFRAMES)
                    outB[fcol * NFRAMES + t] = valid ? (acc[mf][nf][r] + bv) : 0.f;
            }
        }
    }
}

extern "C" void kernel_launch(void* const* d_in, const int* in_sizes, int n_in,
                              void* d_out, int out_size, void* d_ws, size_t ws_size,
                              hipStream_t stream) {
    const float* X    = (const float*)d_in[0];
    const int*   ot   = (const int*)d_in[1];
    const float* W    = (const float*)d_in[2];
    const float* Bias = (const float*)d_in[3];
    const int*   jc   = (const int*)d_in[4];
    float*       out  = (float*)d_out;

    dim3 grid(MTILES * BSZ);   // 768 blocks = 128 samples x 6 M-tiles
    dim3 block(NTHREADS);
    hipLaunchKernelGGL(fused_expert_gemm, grid, block, 0, stream,
                       X, ot, W, Bias, jc, out);
}